// Round 10
// baseline (1165.282 us; speedup 1.0000x reference)
//
#include <hip/hip_runtime.h>
#include <hip/hip_fp16.h>
#include <math.h>

#define B_ 32
#define N_ 1024
#define E_ 2048
#define DD 11   // d = D + Hd = 3 + 8
#define HD 8
#define RTOT ((size_t)B_ * N_ * E_)   // 67,108,864 per R array

// ---------------- input network: H = [tanh(X@Wi+bi), X] ----------------
__global__ void k_input(const float* __restrict__ X, const float* __restrict__ Wi,
                        const float* __restrict__ bi, float* __restrict__ H) {
    int idx = blockIdx.x * 256 + threadIdx.x;
    if (idx >= B_ * N_) return;
    float x0 = X[idx * 3 + 0], x1 = X[idx * 3 + 1], x2 = X[idx * 3 + 2];
    float* h = H + (size_t)idx * DD;
    #pragma unroll
    for (int j = 0; j < HD; j++)
        h[j] = tanhf(x0 * Wi[0 * HD + j] + x1 * Wi[1 * HD + j] + x2 * Wi[2 * HD + j] + bi[j]);
    h[8] = x0; h[9] = x1; h[10] = x2;
}

// ---------------- shared edge MLP ----------------
__device__ inline float edge_mlp(const float* ao, const float* ai,
        const float* __restrict__ We1, const float* __restrict__ be1,
        const float* __restrict__ We2, const float* __restrict__ be2) {
    float h[HD];
    #pragma unroll
    for (int j = 0; j < HD; j++) {
        float acc = be1[j];
        #pragma unroll
        for (int d = 0; d < DD; d++) acc = fmaf(ao[d], We1[d * HD + j], acc);
        #pragma unroll
        for (int d = 0; d < DD; d++) acc = fmaf(ai[d], We1[(DD + d) * HD + j], acc);
        h[j] = tanhf(acc);
    }
    float sacc = be2[0];
    #pragma unroll
    for (int j = 0; j < HD; j++) sacc = fmaf(h[j], We2[j], sacc);
    return 1.f / (1.f + expf(-sacc));
}

// ---------------- fused: transpose-convert + iteration-0 edge (R7, proven) -------
__global__ __launch_bounds__(256) void k_fused(
        const float* __restrict__ Ri, const float* __restrict__ Ro,
        const float* __restrict__ H,
        const float* __restrict__ We1, const float* __restrict__ be1,
        const float* __restrict__ We2, const float* __restrict__ be2,
        __half* __restrict__ RiT, __half* __restrict__ RoT,
        float* __restrict__ wbo, float* __restrict__ wbi) {
    __shared__ unsigned T32[2][64][33];     // 16.9 KB, fp16-packed (2 e per u32)
    float (*red)[64][2 * DD] = reinterpret_cast<float(*)[64][2 * DD]>(&T32[0][0][0]);
    int bid = blockIdx.x;
    int e0 = (bid & 31) << 6;               // 32 e-tiles of 64
    int b  = bid >> 5;
    int tid = threadIdx.x;
    int w = tid >> 6, lane = tid & 63;
    int lr = tid >> 4;                      // staging row 0..15 (+16k)
    int lc = (tid & 15) << 2;               // staging col 0,4,...,60
    int col0 = (tid & 15) << 1;             // u32 col pair base
    int rblk = tid & 7, cc = tid >> 3;      // transpose-out assignment (cc 0..31)
    int wbase = __builtin_amdgcn_readfirstlane(w << 4);
    const float* hp = H + (size_t)b * N_ * DD;

    float ai[DD], ao[DD];
    #pragma unroll
    for (int d = 0; d < DD; d++) { ai[d] = 0.f; ao[d] = 0.f; }

    float4 pa[4];
    auto PRE = [&](const float* Rg, int nb) {
        const float* src = Rg + ((size_t)(b * N_ + nb)) * E_ + e0;
        #pragma unroll
        for (int k = 0; k < 4; k++)
            pa[k] = *(const float4*)(src + (size_t)(lr + (k << 4)) * E_ + lc);
    };
    auto STAGE = [&](int buf) {
        #pragma unroll
        for (int k = 0; k < 4; k++) {
            int r = lr + (k << 4);
            __half2 h2a = __floats2half2_rn(pa[k].x, pa[k].y);
            __half2 h2b = __floats2half2_rn(pa[k].z, pa[k].w);
            T32[buf][r][col0]     = *(unsigned*)&h2a;
            T32[buf][r][col0 + 1] = *(unsigned*)&h2b;
        }
    };
    auto GATHER = [&](int buf, float (&acc)[DD], int nb) {
        #pragma unroll 4
        for (int j = 0; j < 16; j++) {
            int nl = wbase + j;
            unsigned u = T32[buf][nl][lane >> 1];
            __half2 hh = *(__half2*)&u;
            float v = __half2float((lane & 1) ? __high2half(hh) : __low2half(hh));
            #pragma unroll
            for (int d = 0; d < DD; d++)
                acc[d] = fmaf(v, hp[(nb + nl) * DD + d], acc[d]);
        }
    };
    auto TROUT = [&](int buf, __half* __restrict__ RT, int nb) {
        unsigned v[8];
        #pragma unroll
        for (int t = 0; t < 8; t++) v[t] = T32[buf][(rblk << 3) + t][cc];
        uint4 lo, hi;
        lo.x = __builtin_amdgcn_perm(v[1], v[0], 0x05040100u);
        lo.y = __builtin_amdgcn_perm(v[3], v[2], 0x05040100u);
        lo.z = __builtin_amdgcn_perm(v[5], v[4], 0x05040100u);
        lo.w = __builtin_amdgcn_perm(v[7], v[6], 0x05040100u);
        hi.x = __builtin_amdgcn_perm(v[1], v[0], 0x07060302u);
        hi.y = __builtin_amdgcn_perm(v[3], v[2], 0x07060302u);
        hi.z = __builtin_amdgcn_perm(v[5], v[4], 0x07060302u);
        hi.w = __builtin_amdgcn_perm(v[7], v[6], 0x07060302u);
        size_t base = ((size_t)(b * E_ + e0 + (cc << 1))) * N_ + nb + (rblk << 3);
        *(uint4*)(RT + base)      = lo;
        *(uint4*)(RT + base + N_) = hi;
    };

    PRE(Ri, 0);
    for (int nt = 0; nt < 16; nt++) {
        int nb = nt << 6;
        STAGE(nt & 1);
        if (nt < 15) PRE(Ri, nb + 64); else PRE(Ro, 0);
        __syncthreads();
        GATHER(nt & 1, ai, nb);
        TROUT(nt & 1, RiT, nb);
    }
    for (int nt = 0; nt < 16; nt++) {
        int nb = nt << 6;
        STAGE(nt & 1);
        if (nt < 15) PRE(Ro, nb + 64);
        __syncthreads();
        GATHER(nt & 1, ao, nb);
        TROUT(nt & 1, RoT, nb);
    }
    __syncthreads();   // tile buffers free -> reuse as reduction buffer

    if (w) {
        #pragma unroll
        for (int d = 0; d < DD; d++) {
            red[w - 1][lane][d]      = ao[d];
            red[w - 1][lane][DD + d] = ai[d];
        }
    }
    __syncthreads();
    if (w == 0) {
        #pragma unroll
        for (int ww = 0; ww < 3; ww++)
            #pragma unroll
            for (int d = 0; d < DD; d++) {
                ao[d] += red[ww][lane][d];
                ai[d] += red[ww][lane][DD + d];
            }
        float ew = edge_mlp(ao, ai, We1, be1, We2, be2);
        size_t idx = (size_t)b * E_ + e0 + lane;
        #pragma unroll
        for (int d = 0; d < DD; d++) {
            wbo[idx * DD + d] = ew * ao[d];
            wbi[idx * DD + d] = ew * ai[d];
        }
    }
}

// ---------------- edge gather v3: 256B-segment staged fp16 RT ----------------
// grid = B * (E/64); block 256 (4 waves). 4 e-quarters of 16 edges; per quarter
// 8 n-tiles of 16e x 128n. Staging: thread (row=t>>4, c16=t&15) loads uint4 at
// row*N + nb + c16*8 -> 16 threads x 16B = 256B contiguous per e-row (the
// k_edge_f-proven segment size). Double-buffered, 1 barrier/tile.
__global__ __launch_bounds__(256) void k_edge_T3(
        const __half* __restrict__ RiT, const __half* __restrict__ RoT,
        const float* __restrict__ H,
        const float* __restrict__ We1, const float* __restrict__ be1,
        const float* __restrict__ We2, const float* __restrict__ be2,
        float* __restrict__ wbo, float* __restrict__ wbi,
        float* __restrict__ out, int final_) {
    __shared__ unsigned T[2][2][16][67];   // [buf][arr][row][u32 col] 17.2 KB
    __shared__ float red[3][16][2 * DD];   // 4.2 KB
    int bid = blockIdx.x;
    int e0 = (bid & 31) << 6;
    int b  = bid >> 5;
    int tid = threadIdx.x;
    int w = tid >> 6, lane = tid & 63;
    int row = tid >> 4, c16 = tid & 15;    // staging assignment
    int g = lane >> 4, lr = lane & 15;     // gather: lane row lr, col-group g
    const float* hp = H + (size_t)b * N_ * DD;

    float ai[DD], ao[DD];
    uint4 qi, qo;

    auto PRE = [&](int q, int nb) {
        const __half* srcI = RiT + ((size_t)(b * E_ + e0 + (q << 4) + row)) * N_ + nb + (c16 << 3);
        const __half* srcO = RoT + ((size_t)(b * E_ + e0 + (q << 4) + row)) * N_ + nb + (c16 << 3);
        qi = *(const uint4*)srcI;
        qo = *(const uint4*)srcO;
    };
    auto STAGE = [&](int buf) {
        const unsigned* ui = (const unsigned*)&qi;
        const unsigned* uo = (const unsigned*)&qo;
        #pragma unroll
        for (int k = 0; k < 4; k++) {
            T[buf][0][row][(c16 << 2) + k] = ui[k];
            T[buf][1][row][(c16 << 2) + k] = uo[k];
        }
    };
    auto GATHER = [&](int buf, int nb) {
        int colbase = (w << 4) + (g << 2);
        #pragma unroll
        for (int k = 0; k < 4; k++) {
            int col = colbase + k;
            unsigned ui = T[buf][0][lr][col];
            unsigned uo = T[buf][1][lr][col];
            float2 fi = __half22float2(*(__half2*)&ui);
            float2 fo = __half22float2(*(__half2*)&uo);
            const float* h0 = hp + (size_t)(nb + (col << 1)) * DD;
            #pragma unroll
            for (int d = 0; d < DD; d++) {
                float a = h0[d], bb = h0[DD + d];
                ai[d] = fmaf(fi.x, a, ai[d]);
                ai[d] = fmaf(fi.y, bb, ai[d]);
                ao[d] = fmaf(fo.x, a, ao[d]);
                ao[d] = fmaf(fo.y, bb, ao[d]);
            }
        }
    };

    for (int q = 0; q < 4; q++) {
        #pragma unroll
        for (int d = 0; d < DD; d++) { ai[d] = 0.f; ao[d] = 0.f; }
        PRE(q, 0);
        for (int nt = 0; nt < 8; nt++) {
            int nb = nt << 7;
            STAGE(nt & 1);
            if (nt < 7) PRE(q, nb + 128);
            __syncthreads();
            GATHER(nt & 1, nb);
        }
        // reduce 16 partials per edge: in-wave (xor 16, 32), then cross-wave LDS
        #pragma unroll
        for (int d = 0; d < DD; d++) {
            ai[d] += __shfl_xor(ai[d], 16);
            ai[d] += __shfl_xor(ai[d], 32);
            ao[d] += __shfl_xor(ao[d], 16);
            ao[d] += __shfl_xor(ao[d], 32);
        }
        if (w && lane < 16) {
            #pragma unroll
            for (int d = 0; d < DD; d++) {
                red[w - 1][lane][d]      = ao[d];
                red[w - 1][lane][DD + d] = ai[d];
            }
        }
        __syncthreads();
        if (w == 0 && lane < 16) {
            #pragma unroll
            for (int ww = 0; ww < 3; ww++)
                #pragma unroll
                for (int d = 0; d < DD; d++) {
                    ao[d] += red[ww][lane][d];
                    ai[d] += red[ww][lane][DD + d];
                }
            float ew = edge_mlp(ao, ai, We1, be1, We2, be2);
            size_t idx = (size_t)b * E_ + e0 + (q << 4) + lane;
            if (final_) {
                out[idx] = ew;
            } else {
                #pragma unroll
                for (int d = 0; d < DD; d++) {
                    wbo[idx * DD + d] = ew * ao[d];
                    wbi[idx * DD + d] = ew * ai[d];
                }
            }
        }
        __syncthreads();   // red reads done before next quarter's red writes
    }
}

// ---------------- transposed scatter (R4/R7 proven): coalesced in n, no LDS ------
__global__ __launch_bounds__(256) void k_scatter_T(
        const __half* __restrict__ RiT, const __half* __restrict__ RoT,
        const float* __restrict__ wbo, const float* __restrict__ wbi,
        float* __restrict__ part, int NS) {
    int bid = blockIdx.x;
    int nt = bid & 1;
    int s  = (bid >> 1) % NS;
    int b  = bid / (2 * NS);
    int n  = (nt << 9) + (threadIdx.x << 1);
    int eper = E_ / NS;
    int e0 = s * eper;

    const __half* pI = RiT + ((size_t)(b * E_ + e0)) * N_ + n;
    const __half* pO = RoT + ((size_t)(b * E_ + e0)) * N_ + n;
    const float* wo = wbo + ((size_t)(b * E_ + e0)) * DD;  // block-uniform -> s_load
    const float* wi = wbi + ((size_t)(b * E_ + e0)) * DD;

    float mi0[DD], mi1[DD], mo0[DD], mo1[DD];
    #pragma unroll
    for (int d = 0; d < DD; d++) { mi0[d]=0.f; mi1[d]=0.f; mo0[d]=0.f; mo1[d]=0.f; }

    #pragma unroll 4
    for (int e = 0; e < eper; e++) {
        float2 fI = __half22float2(*(const __half2*)(pI + (size_t)e * N_));
        float2 fO = __half22float2(*(const __half2*)(pO + (size_t)e * N_));
        #pragma unroll
        for (int d = 0; d < DD; d++) {
            float a = wo[e * DD + d];
            float c = wi[e * DD + d];
            mi0[d] = fmaf(fI.x, a, mi0[d]);
            mi1[d] = fmaf(fI.y, a, mi1[d]);
            mo0[d] = fmaf(fO.x, c, mo0[d]);
            mo1[d] = fmaf(fO.y, c, mo1[d]);
        }
    }
    size_t bmi = ((size_t)(s * B_ + b)) * DD * N_ + n;
    size_t bmo = ((size_t)((NS + s) * B_ + b)) * DD * N_ + n;
    #pragma unroll
    for (int d = 0; d < DD; d++) {
        *(float2*)&part[bmi + (size_t)d * N_] = make_float2(mi0[d], mi1[d]);
        *(float2*)&part[bmo + (size_t)d * N_] = make_float2(mo0[d], mo1[d]);
    }
}

// ---------------- node finish (proven) ----------------
__global__ void k_node_finish(const float* __restrict__ part,
        const float* __restrict__ Wn1, const float* __restrict__ bn1,
        const float* __restrict__ Wn2, const float* __restrict__ bn2,
        float* __restrict__ H, int NS) {
    int idx = blockIdx.x * 256 + threadIdx.x;
    if (idx >= B_ * N_) return;
    int b = idx / N_, n = idx % N_;

    float mi[DD], mo[DD];
    #pragma unroll
    for (int d = 0; d < DD; d++) { mi[d] = 0.f; mo[d] = 0.f; }
    for (int s = 0; s < NS; s++) {
        size_t pmi = ((size_t)(s * B_ + b)) * DD * N_ + n;
        size_t pmo = ((size_t)((NS + s) * B_ + b)) * DD * N_ + n;
        #pragma unroll
        for (int d = 0; d < DD; d++) {
            mi[d] += part[pmi + (size_t)d * N_];
            mo[d] += part[pmo + (size_t)d * N_];
        }
    }
    float* h = H + (size_t)idx * DD;
    float hold[DD];
    #pragma unroll
    for (int d = 0; d < DD; d++) hold[d] = h[d];

    float t1[HD];
    #pragma unroll
    for (int j = 0; j < HD; j++) {
        float acc = bn1[j];
        #pragma unroll
        for (int d = 0; d < DD; d++) acc = fmaf(mi[d],   Wn1[d * HD + j], acc);
        #pragma unroll
        for (int d = 0; d < DD; d++) acc = fmaf(mo[d],   Wn1[(DD + d) * HD + j], acc);
        #pragma unroll
        for (int d = 0; d < DD; d++) acc = fmaf(hold[d], Wn1[(2 * DD + d) * HD + j], acc);
        t1[j] = tanhf(acc);
    }
    #pragma unroll
    for (int j = 0; j < HD; j++) {
        float acc = bn2[j];
        #pragma unroll
        for (int k = 0; k < HD; k++) acc = fmaf(t1[k], Wn2[k * HD + j], acc);
        h[j] = tanhf(acc);
    }
}

// ================= f32 fallback path (unchanged, proven) =================
__global__ __launch_bounds__(256) void k_edge_f(
        const float* __restrict__ Ri, const float* __restrict__ Ro,
        const float* __restrict__ H,
        const float* __restrict__ We1, const float* __restrict__ be1,
        const float* __restrict__ We2, const float* __restrict__ be2,
        float* __restrict__ wbo, float* __restrict__ wbi,
        float* __restrict__ out, int final_) {
    __shared__ float red[3][64][2 * DD];
    int bid = blockIdx.x;
    int eb = (bid & 31) << 6;
    int b  = bid >> 5;
    int tid = threadIdx.x;
    int w = tid >> 6, lane = tid & 63;
    int e = eb + lane;
    int n0 = w << 8;

    float ao[DD], ai[DD];
    #pragma unroll
    for (int d = 0; d < DD; d++) { ao[d] = 0.f; ai[d] = 0.f; }

    const float* ri = Ri + ((size_t)b * N_ + n0) * E_ + e;
    const float* ro = Ro + ((size_t)b * N_ + n0) * E_ + e;
    int hbase = __builtin_amdgcn_readfirstlane((b * N_ + n0) * DD);
    const float* hp = H + hbase;

    #pragma unroll 4
    for (int n = 0; n < 256; n++) {
        float vi = ri[(size_t)n * E_];
        float vo = ro[(size_t)n * E_];
        #pragma unroll
        for (int d = 0; d < DD; d++) {
            float hv = hp[n * DD + d];
            ao[d] = fmaf(vo, hv, ao[d]);
            ai[d] = fmaf(vi, hv, ai[d]);
        }
    }
    if (w) {
        #pragma unroll
        for (int d = 0; d < DD; d++) {
            red[w - 1][lane][d]      = ao[d];
            red[w - 1][lane][DD + d] = ai[d];
        }
    }
    __syncthreads();
    if (w == 0) {
        #pragma unroll
        for (int ww = 0; ww < 3; ww++)
            #pragma unroll
            for (int d = 0; d < DD; d++) {
                ao[d] += red[ww][lane][d];
                ai[d] += red[ww][lane][DD + d];
            }
        float ew = edge_mlp(ao, ai, We1, be1, We2, be2);
        size_t idx = (size_t)b * E_ + e;
        if (final_) {
            out[idx] = ew;
        } else {
            #pragma unroll
            for (int d = 0; d < DD; d++) {
                wbo[idx * DD + d] = ew * ao[d];
                wbi[idx * DD + d] = ew * ai[d];
            }
        }
    }
}

__global__ __launch_bounds__(256) void k_scatter_f(const float* __restrict__ Ri,
        const float* __restrict__ Ro, const float* __restrict__ wbo,
        const float* __restrict__ wbi, float* __restrict__ part, int NS) {
    __shared__ float TA[256][19];
    __shared__ float TB[256][19];
    int bid = blockIdx.x;
    int nt = bid & 3;
    int s  = (bid >> 2) % NS;
    int b  = bid / (4 * NS);
    int n0 = nt << 8;
    int eper = E_ / NS;
    int e0 = s * eper;
    int tid = threadIdx.x;
    int rF = tid >> 2, cF = (tid & 3) << 2;

    const float* bRi = Ri + ((size_t)b * N_ + n0) * E_ + e0;
    const float* bRo = Ro + ((size_t)b * N_ + n0) * E_ + e0;

    float mi[DD], mo[DD];
    #pragma unroll
    for (int d = 0; d < DD; d++) { mi[d] = 0.f; mo[d] = 0.f; }

    float4 pa[4], pb[4];
    auto LOADC = [&](int ec) {
        #pragma unroll
        for (int k = 0; k < 4; k++) {
            size_t off = (size_t)(rF + (k << 6)) * E_ + ec + cF;
            pa[k] = *(const float4*)(bRi + off);
            pb[k] = *(const float4*)(bRo + off);
        }
    };
    auto WRITEC = [&]() {
        #pragma unroll
        for (int k = 0; k < 4; k++) {
            int row = rF + (k << 6);
            TA[row][cF + 0] = pa[k].x; TA[row][cF + 1] = pa[k].y;
            TA[row][cF + 2] = pa[k].z; TA[row][cF + 3] = pa[k].w;
            TB[row][cF + 0] = pb[k].x; TB[row][cF + 1] = pb[k].y;
            TB[row][cF + 2] = pb[k].z; TB[row][cF + 3] = pb[k].w;
        }
    };

    LOADC(0);
    WRITEC();
    __syncthreads();
    for (int ec = 0; ec < eper; ec += 16) {
        bool more = (ec + 16) < eper;
        if (more) LOADC(ec + 16);
        const float* wo = wbo + ((size_t)b * E_ + e0 + ec) * DD;
        const float* wi = wbi + ((size_t)b * E_ + e0 + ec) * DD;
        #pragma unroll
        for (int j = 0; j < 16; j++) {
            float vA = TA[tid][j];
            float vB = TB[tid][j];
            #pragma unroll
            for (int d = 0; d < DD; d++) {
                mi[d] = fmaf(vA, wo[j * DD + d], mi[d]);
                mo[d] = fmaf(vB, wi[j * DD + d], mo[d]);
            }
        }
        if (more) {
            __syncthreads();
            WRITEC();
            __syncthreads();
        }
    }
    size_t bmi = ((size_t)(s * B_ + b)) * DD * N_ + n0 + tid;
    size_t bmo = ((size_t)((NS + s) * B_ + b)) * DD * N_ + n0 + tid;
    #pragma unroll
    for (int d = 0; d < DD; d++) {
        part[bmi + (size_t)d * N_] = mi[d];
        part[bmo + (size_t)d * N_] = mo[d];
    }
}

extern "C" void kernel_launch(void* const* d_in, const int* in_sizes, int n_in,
                              void* d_out, int out_size, void* d_ws, size_t ws_size,
                              hipStream_t stream) {
    const float* X   = (const float*)d_in[0];
    const float* Ri  = (const float*)d_in[1];
    const float* Ro  = (const float*)d_in[2];
    const float* Wi  = (const float*)d_in[3];
    const float* bi  = (const float*)d_in[4];
    const float* We1 = (const float*)d_in[5];
    const float* be1 = (const float*)d_in[6];
    const float* We2 = (const float*)d_in[7];
    const float* be2 = (const float*)d_in[8];
    const float* Wn1 = (const float*)d_in[9];
    const float* bn1 = (const float*)d_in[10];
    const float* Wn2 = (const float*)d_in[11];
    const float* bn2 = (const float*)d_in[12];
    float* out = (float*)d_out;

    const size_t H_FL  = (size_t)B_ * N_ * DD;
    const size_t WB_FL = (size_t)B_ * E_ * DD;
    auto spart_fl = [](int ns) { return 2ull * ns * B_ * DD * N_; };
    auto needT = [&](int ns) {
        return 2ull * RTOT * 2 + 4ull * (H_FL + 2 * WB_FL + spart_fl(ns));
    };

    int NS = 16;
    if (needT(NS) > ws_size) NS = 8;

    if (needT(NS) <= ws_size) {
        // ---------------- transposed-fp16 path ----------------
        char* p = (char*)d_ws;
        __half* RiT = (__half*)p;  p += RTOT * 2;
        __half* RoT = (__half*)p;  p += RTOT * 2;
        float* H    = (float*)p;   p += H_FL * 4;
        float* wbo  = (float*)p;   p += WB_FL * 4;
        float* wbi  = (float*)p;   p += WB_FL * 4;
        float* spart = (float*)p;

        k_input<<<(B_ * N_ + 255) / 256, 256, 0, stream>>>(X, Wi, bi, H);
        k_fused<<<B_ * 32, 256, 0, stream>>>(Ri, Ro, H, We1, be1, We2, be2,
                                             RiT, RoT, wbo, wbi);
        for (int it = 0; it < 3; it++) {
            k_scatter_T<<<B_ * 2 * NS, 256, 0, stream>>>(RiT, RoT, wbo, wbi, spart, NS);
            k_node_finish<<<(B_ * N_ + 255) / 256, 256, 0, stream>>>(
                spart, Wn1, bn1, Wn2, bn2, H, NS);
            k_edge_T3<<<B_ * 32, 256, 0, stream>>>(RiT, RoT, H, We1, be1, We2, be2,
                                                   wbo, wbi, out, it == 2 ? 1 : 0);
        }
    } else {
        // ---------------- f32 fallback ----------------
        size_t fl = ws_size / sizeof(float);
        int NSS = 8;
        auto need = [&](int s) { return H_FL + 2 * WB_FL + spart_fl(s); };
        if (need(NSS) > fl) NSS = 4;
        if (need(NSS) > fl) NSS = 2;

        float* ws    = (float*)d_ws;
        float* H     = ws;  ws += H_FL;
        float* wbo   = ws;  ws += WB_FL;
        float* wbi   = ws;  ws += WB_FL;
        float* spart = ws;

        k_input<<<(B_ * N_ + 255) / 256, 256, 0, stream>>>(X, Wi, bi, H);
        for (int it = 0; it < 3; it++) {
            k_edge_f<<<B_ * 32, 256, 0, stream>>>(Ri, Ro, H, We1, be1, We2, be2,
                                                  wbo, wbi, out, 0);
            k_scatter_f<<<B_ * 4 * NSS, 256, 0, stream>>>(
                Ri, Ro, wbo, wbi, spart, NSS);
            k_node_finish<<<(B_ * N_ + 255) / 256, 256, 0, stream>>>(
                spart, Wn1, bn1, Wn2, bn2, H, NSS);
        }
        k_edge_f<<<B_ * 32, 256, 0, stream>>>(Ri, Ro, H, We1, be1, We2, be2,
                                              wbo, wbi, out, 1);
    }
}

// Round 11
// 580.027 us; speedup vs baseline: 2.0090x; 2.0090x over previous
//
#include <hip/hip_runtime.h>
#include <hip/hip_fp16.h>
#include <math.h>

#define B_ 32
#define N_ 1024
#define E_ 2048
#define DD 11   // d = D + Hd = 3 + 8
#define HD 8
#define RTOT ((size_t)B_ * N_ * E_)   // 67,108,864 per R array

// ---------------- input network: H = [tanh(X@Wi+bi), X] ----------------
__global__ void k_input(const float* __restrict__ X, const float* __restrict__ Wi,
                        const float* __restrict__ bi, float* __restrict__ H) {
    int idx = blockIdx.x * 256 + threadIdx.x;
    if (idx >= B_ * N_) return;
    float x0 = X[idx * 3 + 0], x1 = X[idx * 3 + 1], x2 = X[idx * 3 + 2];
    float* h = H + (size_t)idx * DD;
    #pragma unroll
    for (int j = 0; j < HD; j++)
        h[j] = tanhf(x0 * Wi[0 * HD + j] + x1 * Wi[1 * HD + j] + x2 * Wi[2 * HD + j] + bi[j]);
    h[8] = x0; h[9] = x1; h[10] = x2;
}

// ---------------- shared edge MLP ----------------
__device__ inline float edge_mlp(const float* ao, const float* ai,
        const float* __restrict__ We1, const float* __restrict__ be1,
        const float* __restrict__ We2, const float* __restrict__ be2) {
    float h[HD];
    #pragma unroll
    for (int j = 0; j < HD; j++) {
        float acc = be1[j];
        #pragma unroll
        for (int d = 0; d < DD; d++) acc = fmaf(ao[d], We1[d * HD + j], acc);
        #pragma unroll
        for (int d = 0; d < DD; d++) acc = fmaf(ai[d], We1[(DD + d) * HD + j], acc);
        h[j] = tanhf(acc);
    }
    float sacc = be2[0];
    #pragma unroll
    for (int j = 0; j < HD; j++) sacc = fmaf(h[j], We2[j], sacc);
    return 1.f / (1.f + expf(-sacc));
}

// pw[e][0:8]=ew*ao@Wn1[rows 0:11], pw[e][8:16]=ew*ai@Wn1[rows 11:22] (R9-proven)
__device__ inline void write_pw(float* __restrict__ pw, size_t eidx, float ew,
        const float* ao, const float* ai, const float* __restrict__ Wn1) {
    float v[16];
    #pragma unroll
    for (int j = 0; j < HD; j++) {
        float a0 = 0.f, a1 = 0.f;
        #pragma unroll
        for (int d = 0; d < DD; d++) {
            a0 = fmaf(ao[d], Wn1[d * HD + j], a0);
            a1 = fmaf(ai[d], Wn1[(DD + d) * HD + j], a1);
        }
        v[j] = ew * a0; v[HD + j] = ew * a1;
    }
    float* dst = pw + eidx * 16;
    #pragma unroll
    for (int k = 0; k < 4; k++)
        *(float4*)(dst + 4 * k) = *(float4*)(v + 4 * k);
}

// ---------------- fused: transpose-convert + iteration-0 edge (R7/R9 proven) -----
__global__ __launch_bounds__(256) void k_fused(
        const float* __restrict__ Ri, const float* __restrict__ Ro,
        const float* __restrict__ H,
        const float* __restrict__ We1, const float* __restrict__ be1,
        const float* __restrict__ We2, const float* __restrict__ be2,
        const float* __restrict__ Wn1,
        __half* __restrict__ RiT, __half* __restrict__ RoT,
        float* __restrict__ pw) {
    __shared__ unsigned T32[2][64][33];     // 16.9 KB, fp16-packed (2 e per u32)
    float (*red)[64][2 * DD] = reinterpret_cast<float(*)[64][2 * DD]>(&T32[0][0][0]);
    int bid = blockIdx.x;
    int e0 = (bid & 31) << 6;
    int b  = bid >> 5;
    int tid = threadIdx.x;
    int w = tid >> 6, lane = tid & 63;
    int lr = tid >> 4;
    int lc = (tid & 15) << 2;
    int col0 = (tid & 15) << 1;
    int rblk = tid & 7, cc = tid >> 3;
    int wbase = __builtin_amdgcn_readfirstlane(w << 4);
    const float* hp = H + (size_t)b * N_ * DD;

    float ai[DD], ao[DD];
    #pragma unroll
    for (int d = 0; d < DD; d++) { ai[d] = 0.f; ao[d] = 0.f; }

    float4 pa[4];
    auto PRE = [&](const float* Rg, int nb) {
        const float* src = Rg + ((size_t)(b * N_ + nb)) * E_ + e0;
        #pragma unroll
        for (int k = 0; k < 4; k++)
            pa[k] = *(const float4*)(src + (size_t)(lr + (k << 4)) * E_ + lc);
    };
    auto STAGE = [&](int buf) {
        #pragma unroll
        for (int k = 0; k < 4; k++) {
            int r = lr + (k << 4);
            __half2 h2a = __floats2half2_rn(pa[k].x, pa[k].y);
            __half2 h2b = __floats2half2_rn(pa[k].z, pa[k].w);
            T32[buf][r][col0]     = *(unsigned*)&h2a;
            T32[buf][r][col0 + 1] = *(unsigned*)&h2b;
        }
    };
    auto GATHER = [&](int buf, float (&acc)[DD], int nb) {
        #pragma unroll 4
        for (int j = 0; j < 16; j++) {
            int nl = wbase + j;
            unsigned u = T32[buf][nl][lane >> 1];
            __half2 hh = *(__half2*)&u;
            float v = __half2float((lane & 1) ? __high2half(hh) : __low2half(hh));
            #pragma unroll
            for (int d = 0; d < DD; d++)
                acc[d] = fmaf(v, hp[(nb + nl) * DD + d], acc[d]);
        }
    };
    auto TROUT = [&](int buf, __half* __restrict__ RT, int nb) {
        unsigned v[8];
        #pragma unroll
        for (int t = 0; t < 8; t++) v[t] = T32[buf][(rblk << 3) + t][cc];
        uint4 lo, hi;
        lo.x = __builtin_amdgcn_perm(v[1], v[0], 0x05040100u);
        lo.y = __builtin_amdgcn_perm(v[3], v[2], 0x05040100u);
        lo.z = __builtin_amdgcn_perm(v[5], v[4], 0x05040100u);
        lo.w = __builtin_amdgcn_perm(v[7], v[6], 0x05040100u);
        hi.x = __builtin_amdgcn_perm(v[1], v[0], 0x07060302u);
        hi.y = __builtin_amdgcn_perm(v[3], v[2], 0x07060302u);
        hi.z = __builtin_amdgcn_perm(v[5], v[4], 0x07060302u);
        hi.w = __builtin_amdgcn_perm(v[7], v[6], 0x07060302u);
        size_t base = ((size_t)(b * E_ + e0 + (cc << 1))) * N_ + nb + (rblk << 3);
        *(uint4*)(RT + base)      = lo;
        *(uint4*)(RT + base + N_) = hi;
    };

    PRE(Ri, 0);
    for (int nt = 0; nt < 16; nt++) {
        int nb = nt << 6;
        STAGE(nt & 1);
        if (nt < 15) PRE(Ri, nb + 64); else PRE(Ro, 0);
        __syncthreads();
        GATHER(nt & 1, ai, nb);
        TROUT(nt & 1, RiT, nb);
    }
    for (int nt = 0; nt < 16; nt++) {
        int nb = nt << 6;
        STAGE(nt & 1);
        if (nt < 15) PRE(Ro, nb + 64);
        __syncthreads();
        GATHER(nt & 1, ao, nb);
        TROUT(nt & 1, RoT, nb);
    }
    __syncthreads();   // tile buffers free -> reuse as reduction buffer

    if (w) {
        #pragma unroll
        for (int d = 0; d < DD; d++) {
            red[w - 1][lane][d]      = ao[d];
            red[w - 1][lane][DD + d] = ai[d];
        }
    }
    __syncthreads();
    if (w == 0) {
        #pragma unroll
        for (int ww = 0; ww < 3; ww++)
            #pragma unroll
            for (int d = 0; d < DD; d++) {
                ao[d] += red[ww][lane][d];
                ai[d] += red[ww][lane][DD + d];
            }
        float ew = edge_mlp(ao, ai, We1, be1, We2, be2);
        write_pw(pw, (size_t)b * E_ + e0 + lane, ew, ao, ai, Wn1);
    }
}

// ---------------- edge gather + MLP from transposed fp16, LDS-staged (R7/R9) -----
__global__ __launch_bounds__(256) void k_edge_T2(
        const __half* __restrict__ RiT, const __half* __restrict__ RoT,
        const float* __restrict__ H,
        const float* __restrict__ We1, const float* __restrict__ be1,
        const float* __restrict__ We2, const float* __restrict__ be2,
        const float* __restrict__ Wn1,
        float* __restrict__ pw, float* __restrict__ out, int final_) {
    __shared__ unsigned T[2][2][64][33];    // [buf][arr][e-row][u32 n-pair] 33.8 KB
    float (*red)[64][2 * DD] = reinterpret_cast<float(*)[64][2 * DD]>(&T[0][0][0][0]);
    int bid = blockIdx.x;
    int e0 = (bid & 31) << 6;
    int b  = bid >> 5;
    int tid = threadIdx.x;
    int w = tid >> 6, lane = tid & 63;
    int wrf = __builtin_amdgcn_readfirstlane(w);
    int r = tid >> 2, q = tid & 3;

    const __half* baseI = RiT + ((size_t)(b * E_ + e0 + r)) * N_ + (q << 3);
    const __half* baseO = RoT + ((size_t)(b * E_ + e0 + r)) * N_ + (q << 3);
    const float* hp = H + (size_t)b * N_ * DD;

    float ai[DD], ao[DD];
    #pragma unroll
    for (int d = 0; d < DD; d++) { ai[d] = 0.f; ao[d] = 0.f; }

    uint4 qi[2], qo[2];
    auto PRE = [&](int nb) {
        qi[0] = *(const uint4*)(baseI + nb);
        qi[1] = *(const uint4*)(baseI + nb + 32);
        qo[0] = *(const uint4*)(baseO + nb);
        qo[1] = *(const uint4*)(baseO + nb + 32);
    };
    auto STAGE = [&](int buf) {
        const unsigned* ui = (const unsigned*)&qi[0];
        const unsigned* uo = (const unsigned*)&qo[0];
        #pragma unroll
        for (int k = 0; k < 4; k++) {
            T[buf][0][r][(q << 2) + k]      = ui[k];
            T[buf][0][r][16 + (q << 2) + k] = ui[4 + k];
            T[buf][1][r][(q << 2) + k]      = uo[k];
            T[buf][1][r][16 + (q << 2) + k] = uo[4 + k];
        }
    };
    auto GATHER = [&](int buf, int nb) {
        #pragma unroll
        for (int k = 0; k < 8; k++) {
            int c = (wrf << 3) + k;
            unsigned ui = T[buf][0][lane][c];
            unsigned uo = T[buf][1][lane][c];
            float2 fi = __half22float2(*(__half2*)&ui);
            float2 fo = __half22float2(*(__half2*)&uo);
            const float* h0 = hp + (size_t)(nb + (c << 1)) * DD;
            #pragma unroll
            for (int d = 0; d < DD; d++) {
                float a = h0[d], bb = h0[DD + d];
                ai[d] = fmaf(fi.x, a, ai[d]);
                ai[d] = fmaf(fi.y, bb, ai[d]);
                ao[d] = fmaf(fo.x, a, ao[d]);
                ao[d] = fmaf(fo.y, bb, ao[d]);
            }
        }
    };

    PRE(0);
    for (int nt = 0; nt < 16; nt++) {
        int nb = nt << 6;
        STAGE(nt & 1);
        if (nt < 15) PRE(nb + 64);
        __syncthreads();
        GATHER(nt & 1, nb);
    }
    __syncthreads();

    if (w) {
        #pragma unroll
        for (int d = 0; d < DD; d++) {
            red[w - 1][lane][d]      = ao[d];
            red[w - 1][lane][DD + d] = ai[d];
        }
    }
    __syncthreads();
    if (w == 0) {
        #pragma unroll
        for (int ww = 0; ww < 3; ww++)
            #pragma unroll
            for (int d = 0; d < DD; d++) {
                ao[d] += red[ww][lane][d];
                ai[d] += red[ww][lane][DD + d];
            }
        float ew = edge_mlp(ao, ai, We1, be1, We2, be2);
        size_t eidx = (size_t)b * E_ + e0 + lane;
        if (final_) {
            out[eidx] = ew;
        } else {
            write_pw(pw, eidx, ew, ao, ai, Wn1);
        }
    }
}

// ---------------- projected scatter: R7 access pattern, 16-dim accumulators ------
// accI[j] = sum_e RiT[e,n]*pw[e][j], accO[j] = sum_e RoT[e,n]*pw[e][8+j].
// grid = B * 2(n-halves) * NS; lane owns 2 consecutive n. part[s][b][n][16].
__global__ __launch_bounds__(256) void k_scatter_P(
        const __half* __restrict__ RiT, const __half* __restrict__ RoT,
        const float* __restrict__ pw, float* __restrict__ part, int NS) {
    int bid = blockIdx.x;
    int nt = bid & 1;
    int s  = (bid >> 1) % NS;
    int b  = bid / (2 * NS);
    int n  = (nt << 9) + (threadIdx.x << 1);
    int eper = E_ / NS;
    int e0 = s * eper;

    const __half* pI = RiT + ((size_t)(b * E_ + e0)) * N_ + n;
    const __half* pO = RoT + ((size_t)(b * E_ + e0)) * N_ + n;
    const float* pwb = pw + ((size_t)(b * E_ + e0)) * 16;   // block-uniform -> s_load

    float aI0[HD], aI1[HD], aO0[HD], aO1[HD];
    #pragma unroll
    for (int j = 0; j < HD; j++) { aI0[j]=0.f; aI1[j]=0.f; aO0[j]=0.f; aO1[j]=0.f; }

    #pragma unroll 4
    for (int e = 0; e < eper; e++) {
        float2 fI = __half22float2(*(const __half2*)(pI + (size_t)e * N_));
        float2 fO = __half22float2(*(const __half2*)(pO + (size_t)e * N_));
        const float* pe = pwb + e * 16;
        #pragma unroll
        for (int j = 0; j < HD; j++) {
            float po = pe[j], pi = pe[HD + j];
            aI0[j] = fmaf(fI.x, po, aI0[j]);
            aI1[j] = fmaf(fI.y, po, aI1[j]);
            aO0[j] = fmaf(fO.x, pi, aO0[j]);
            aO1[j] = fmaf(fO.y, pi, aO1[j]);
        }
    }
    // part[s][b][n][0:8]=accI, [8:16]=accO; two consecutive n rows per lane
    float* dst = part + (((size_t)(s * B_ + b)) * N_ + n) * 16;
    float v[32];
    #pragma unroll
    for (int j = 0; j < HD; j++) {
        v[j] = aI0[j]; v[HD + j] = aO0[j];
        v[16 + j] = aI1[j]; v[24 + j] = aO1[j];
    }
    #pragma unroll
    for (int k = 0; k < 8; k++)
        *(float4*)(dst + 4 * k) = *(float4*)(v + 4 * k);
}

// ---------------- node finish v2: sum 16-dim partials + R9-proven tail -----------
__global__ void k_node_fin(const float* __restrict__ part,
        const float* __restrict__ Wn1, const float* __restrict__ bn1,
        const float* __restrict__ Wn2, const float* __restrict__ bn2,
        float* __restrict__ H, int NS) {
    int idx = blockIdx.x * 256 + threadIdx.x;   // over B*N
    if (idx >= B_ * N_) return;
    int b = idx / N_, n = idx % N_;

    float acc[16];
    #pragma unroll
    for (int j = 0; j < 16; j++) acc[j] = 0.f;
    for (int s = 0; s < NS; s++) {
        const float* p = part + (((size_t)(s * B_ + b)) * N_ + n) * 16;
        #pragma unroll
        for (int k = 0; k < 4; k++) {
            float4 f = *(const float4*)(p + 4 * k);
            acc[4 * k + 0] += f.x; acc[4 * k + 1] += f.y;
            acc[4 * k + 2] += f.z; acc[4 * k + 3] += f.w;
        }
    }
    float* hrow = H + (size_t)idx * DD;
    float hold[DD];
    #pragma unroll
    for (int d = 0; d < DD; d++) hold[d] = hrow[d];

    float t1[HD];
    #pragma unroll
    for (int j = 0; j < HD; j++) {
        float a = bn1[j] + acc[j] + acc[HD + j];
        #pragma unroll
        for (int d = 0; d < DD; d++)
            a = fmaf(hold[d], Wn1[(2 * DD + d) * HD + j], a);
        t1[j] = tanhf(a);
    }
    #pragma unroll
    for (int j = 0; j < HD; j++) {
        float a = bn2[j];
        #pragma unroll
        for (int k = 0; k < HD; k++) a = fmaf(t1[k], Wn2[k * HD + j], a);
        hrow[j] = tanhf(a);
    }
}

// ================= f32 fallback path (unchanged, proven) =================
__global__ __launch_bounds__(256) void k_edge_f(
        const float* __restrict__ Ri, const float* __restrict__ Ro,
        const float* __restrict__ H,
        const float* __restrict__ We1, const float* __restrict__ be1,
        const float* __restrict__ We2, const float* __restrict__ be2,
        float* __restrict__ wbo, float* __restrict__ wbi,
        float* __restrict__ out, int final_) {
    __shared__ float red[3][64][2 * DD];
    int bid = blockIdx.x;
    int eb = (bid & 31) << 6;
    int b  = bid >> 5;
    int tid = threadIdx.x;
    int w = tid >> 6, lane = tid & 63;
    int e = eb + lane;
    int n0 = w << 8;

    float ao[DD], ai[DD];
    #pragma unroll
    for (int d = 0; d < DD; d++) { ao[d] = 0.f; ai[d] = 0.f; }

    const float* ri = Ri + ((size_t)b * N_ + n0) * E_ + e;
    const float* ro = Ro + ((size_t)b * N_ + n0) * E_ + e;
    int hbase = __builtin_amdgcn_readfirstlane((b * N_ + n0) * DD);
    const float* hp = H + hbase;

    #pragma unroll 4
    for (int n = 0; n < 256; n++) {
        float vi = ri[(size_t)n * E_];
        float vo = ro[(size_t)n * E_];
        #pragma unroll
        for (int d = 0; d < DD; d++) {
            float hv = hp[n * DD + d];
            ao[d] = fmaf(vo, hv, ao[d]);
            ai[d] = fmaf(vi, hv, ai[d]);
        }
    }
    if (w) {
        #pragma unroll
        for (int d = 0; d < DD; d++) {
            red[w - 1][lane][d]      = ao[d];
            red[w - 1][lane][DD + d] = ai[d];
        }
    }
    __syncthreads();
    if (w == 0) {
        #pragma unroll
        for (int ww = 0; ww < 3; ww++)
            #pragma unroll
            for (int d = 0; d < DD; d++) {
                ao[d] += red[ww][lane][d];
                ai[d] += red[ww][lane][DD + d];
            }
        float ew = edge_mlp(ao, ai, We1, be1, We2, be2);
        size_t idx = (size_t)b * E_ + e;
        if (final_) {
            out[idx] = ew;
        } else {
            #pragma unroll
            for (int d = 0; d < DD; d++) {
                wbo[idx * DD + d] = ew * ao[d];
                wbi[idx * DD + d] = ew * ai[d];
            }
        }
    }
}

__global__ __launch_bounds__(256) void k_scatter_f(const float* __restrict__ Ri,
        const float* __restrict__ Ro, const float* __restrict__ wbo,
        const float* __restrict__ wbi, float* __restrict__ part, int NS) {
    __shared__ float TA[256][19];
    __shared__ float TB[256][19];
    int bid = blockIdx.x;
    int nt = bid & 3;
    int s  = (bid >> 2) % NS;
    int b  = bid / (4 * NS);
    int n0 = nt << 8;
    int eper = E_ / NS;
    int e0 = s * eper;
    int tid = threadIdx.x;
    int rF = tid >> 2, cF = (tid & 3) << 2;

    const float* bRi = Ri + ((size_t)b * N_ + n0) * E_ + e0;
    const float* bRo = Ro + ((size_t)b * N_ + n0) * E_ + e0;

    float mi[DD], mo[DD];
    #pragma unroll
    for (int d = 0; d < DD; d++) { mi[d] = 0.f; mo[d] = 0.f; }

    float4 pa[4], pb[4];
    auto LOADC = [&](int ec) {
        #pragma unroll
        for (int k = 0; k < 4; k++) {
            size_t off = (size_t)(rF + (k << 6)) * E_ + ec + cF;
            pa[k] = *(const float4*)(bRi + off);
            pb[k] = *(const float4*)(bRo + off);
        }
    };
    auto WRITEC = [&]() {
        #pragma unroll
        for (int k = 0; k < 4; k++) {
            int row = rF + (k << 6);
            TA[row][cF + 0] = pa[k].x; TA[row][cF + 1] = pa[k].y;
            TA[row][cF + 2] = pa[k].z; TA[row][cF + 3] = pa[k].w;
            TB[row][cF + 0] = pb[k].x; TB[row][cF + 1] = pb[k].y;
            TB[row][cF + 2] = pb[k].z; TB[row][cF + 3] = pb[k].w;
        }
    };

    LOADC(0);
    WRITEC();
    __syncthreads();
    for (int ec = 0; ec < eper; ec += 16) {
        bool more = (ec + 16) < eper;
        if (more) LOADC(ec + 16);
        const float* wo = wbo + ((size_t)b * E_ + e0 + ec) * DD;
        const float* wi = wbi + ((size_t)b * E_ + e0 + ec) * DD;
        #pragma unroll
        for (int j = 0; j < 16; j++) {
            float vA = TA[tid][j];
            float vB = TB[tid][j];
            #pragma unroll
            for (int d = 0; d < DD; d++) {
                mi[d] = fmaf(vA, wo[j * DD + d], mi[d]);
                mo[d] = fmaf(vB, wi[j * DD + d], mo[d]);
            }
        }
        if (more) {
            __syncthreads();
            WRITEC();
            __syncthreads();
        }
    }
    size_t bmi = ((size_t)(s * B_ + b)) * DD * N_ + n0 + tid;
    size_t bmo = ((size_t)((NS + s) * B_ + b)) * DD * N_ + n0 + tid;
    #pragma unroll
    for (int d = 0; d < DD; d++) {
        part[bmi + (size_t)d * N_] = mi[d];
        part[bmo + (size_t)d * N_] = mo[d];
    }
}

__global__ void k_node_finish(const float* __restrict__ part,
        const float* __restrict__ Wn1, const float* __restrict__ bn1,
        const float* __restrict__ Wn2, const float* __restrict__ bn2,
        float* __restrict__ H, int NS) {
    int idx = blockIdx.x * 256 + threadIdx.x;
    if (idx >= B_ * N_) return;
    int b = idx / N_, n = idx % N_;

    float mi[DD], mo[DD];
    #pragma unroll
    for (int d = 0; d < DD; d++) { mi[d] = 0.f; mo[d] = 0.f; }
    for (int s = 0; s < NS; s++) {
        size_t pmi = ((size_t)(s * B_ + b)) * DD * N_ + n;
        size_t pmo = ((size_t)((NS + s) * B_ + b)) * DD * N_ + n;
        #pragma unroll
        for (int d = 0; d < DD; d++) {
            mi[d] += part[pmi + (size_t)d * N_];
            mo[d] += part[pmo + (size_t)d * N_];
        }
    }
    float* h = H + (size_t)idx * DD;
    float hold[DD];
    #pragma unroll
    for (int d = 0; d < DD; d++) hold[d] = h[d];

    float t1[HD];
    #pragma unroll
    for (int j = 0; j < HD; j++) {
        float acc = bn1[j];
        #pragma unroll
        for (int d = 0; d < DD; d++) acc = fmaf(mi[d],   Wn1[d * HD + j], acc);
        #pragma unroll
        for (int d = 0; d < DD; d++) acc = fmaf(mo[d],   Wn1[(DD + d) * HD + j], acc);
        #pragma unroll
        for (int d = 0; d < DD; d++) acc = fmaf(hold[d], Wn1[(2 * DD + d) * HD + j], acc);
        t1[j] = tanhf(acc);
    }
    #pragma unroll
    for (int j = 0; j < HD; j++) {
        float acc = bn2[j];
        #pragma unroll
        for (int k = 0; k < HD; k++) acc = fmaf(t1[k], Wn2[k * HD + j], acc);
        h[j] = tanhf(acc);
    }
}

extern "C" void kernel_launch(void* const* d_in, const int* in_sizes, int n_in,
                              void* d_out, int out_size, void* d_ws, size_t ws_size,
                              hipStream_t stream) {
    const float* X   = (const float*)d_in[0];
    const float* Ri  = (const float*)d_in[1];
    const float* Ro  = (const float*)d_in[2];
    const float* Wi  = (const float*)d_in[3];
    const float* bi  = (const float*)d_in[4];
    const float* We1 = (const float*)d_in[5];
    const float* be1 = (const float*)d_in[6];
    const float* We2 = (const float*)d_in[7];
    const float* be2 = (const float*)d_in[8];
    const float* Wn1 = (const float*)d_in[9];
    const float* bn1 = (const float*)d_in[10];
    const float* Wn2 = (const float*)d_in[11];
    const float* bn2 = (const float*)d_in[12];
    float* out = (float*)d_out;

    const size_t H_FL  = (size_t)B_ * N_ * DD;
    const size_t WB_FL = (size_t)B_ * E_ * DD;
    const size_t PW_FL = (size_t)B_ * E_ * 16;
    auto ppart_fl = [](int ns) { return (size_t)ns * B_ * N_ * 16; };
    auto needT = [&](int ns) {
        return 2ull * RTOT * 2 + 4ull * (H_FL + PW_FL + ppart_fl(ns));
    };

    int NS = 16;
    if (needT(NS) > ws_size) NS = 8;

    if (needT(NS) <= ws_size) {
        // ---------------- transposed-fp16 projected path ----------------
        char* p = (char*)d_ws;
        __half* RiT = (__half*)p;  p += RTOT * 2;
        __half* RoT = (__half*)p;  p += RTOT * 2;
        float* H    = (float*)p;   p += H_FL * 4;
        float* pw   = (float*)p;   p += PW_FL * 4;
        float* part = (float*)p;

        k_input<<<(B_ * N_ + 255) / 256, 256, 0, stream>>>(X, Wi, bi, H);
        k_fused<<<B_ * 32, 256, 0, stream>>>(Ri, Ro, H, We1, be1, We2, be2, Wn1,
                                             RiT, RoT, pw);
        for (int it = 0; it < 3; it++) {
            k_scatter_P<<<B_ * 2 * NS, 256, 0, stream>>>(RiT, RoT, pw, part, NS);
            k_node_fin<<<(B_ * N_ + 255) / 256, 256, 0, stream>>>(
                part, Wn1, bn1, Wn2, bn2, H, NS);
            k_edge_T2<<<B_ * 32, 256, 0, stream>>>(RiT, RoT, H, We1, be1, We2, be2,
                                                   Wn1, pw, out, it == 2 ? 1 : 0);
        }
    } else {
        // ---------------- f32 fallback ----------------
        size_t fl = ws_size / sizeof(float);
        auto spart_fl = [](int ns) { return 2ull * ns * B_ * DD * N_; };
        int NSS = 8;
        auto need = [&](int s) { return H_FL + 2 * WB_FL + spart_fl(s); };
        if (need(NSS) > fl) NSS = 4;
        if (need(NSS) > fl) NSS = 2;

        float* ws    = (float*)d_ws;
        float* H     = ws;  ws += H_FL;
        float* wbo   = ws;  ws += WB_FL;
        float* wbi   = ws;  ws += WB_FL;
        float* spart = ws;

        k_input<<<(B_ * N_ + 255) / 256, 256, 0, stream>>>(X, Wi, bi, H);
        for (int it = 0; it < 3; it++) {
            k_edge_f<<<B_ * 32, 256, 0, stream>>>(Ri, Ro, H, We1, be1, We2, be2,
                                                  wbo, wbi, out, 0);
            k_scatter_f<<<B_ * 4 * NSS, 256, 0, stream>>>(
                Ri, Ro, wbo, wbi, spart, NSS);
            k_node_finish<<<(B_ * N_ + 255) / 256, 256, 0, stream>>>(
                spart, Wn1, bn1, Wn2, bn2, H, NSS);
        }
        k_edge_f<<<B_ * 32, 256, 0, stream>>>(Ri, Ro, H, We1, be1, We2, be2,
                                              wbo, wbi, out, 1);
    }
}